// Round 3
// baseline (1822.106 us; speedup 1.0000x reference)
//
#include <hip/hip_runtime.h>

#define DIM   256
#define HW_   1024
#define NROWS 32768
#define KEMB  4096

// ---------------- ws layout ----------------
// [0,       131072)   int   idx[32768]
// [131072,  262144)   float S[32768]
// [262144,  278528)   float E[4096]
// [278528,  278536)   double loss_sum
// [524288,  4718592)  short ebuf[4096*512]   (e1 then e2 per j, 256 each)
// [4718592, 8912896)  float minima[32768*32] (per-row per-128j block min)
#define WS_S_OFF    131072
#define WS_E_OFF    262144
#define WS_LOSS_OFF 278528
#define WS_EBUF_OFF 524288
#define WS_MIN_OFF  4718592
#define WS_NEEDED   8912896
#define FILTER_T    1.0e-3f

typedef __attribute__((ext_vector_type(8))) short bf16x8;
typedef __attribute__((ext_vector_type(4))) float f32x4;

// ---------- K1: numpy-pairwise row sums of squares ----------
__device__ __forceinline__ float np_sumsq_128(const float* q, int stride) {
#pragma clang fp contract(off)
  float r[8];
#pragma unroll
  for (int i = 0; i < 8; ++i) { float v = q[i * stride]; r[i] = v * v; }
  for (int blk = 8; blk < 128; blk += 8) {
#pragma unroll
    for (int i = 0; i < 8; ++i) {
      float v = q[(blk + i) * stride];
      float sq = v * v;
      r[i] = r[i] + sq;
    }
  }
  return ((r[0] + r[1]) + (r[2] + r[3])) + ((r[4] + r[5]) + (r[6] + r[7]));
}

__global__ __launch_bounds__(256) void norms_kernel(
    const float* __restrict__ z, const float* __restrict__ emb,
    float* __restrict__ S, float* __restrict__ E) {
#pragma clang fp contract(off)
  int t = blockIdx.x * 256 + threadIdx.x;
  if (t < NROWS) {
    int b = t >> 10, hw = t & 1023;
    const float* p = z + (size_t)b * (DIM * HW_) + hw;
    float s0 = np_sumsq_128(p, HW_);
    float s1 = np_sumsq_128(p + 128 * HW_, HW_);
    S[t] = s0 + s1;
  } else if (t < NROWS + KEMB) {
    int j = t - NROWS;
    const float* p = emb + (size_t)j * DIM;
    float s0 = np_sumsq_128(p, 1);
    float s1 = np_sumsq_128(p + 128, 1);
    E[j] = s0 + s1;
  }
}

// ---------- Kpre: split embedding into bf16 hi/lo ----------
__global__ __launch_bounds__(256) void pack_e_kernel(
    const float* __restrict__ emb, short* __restrict__ ebuf) {
#pragma clang fp contract(off)
  int j = blockIdx.x, k = threadIdx.x;
  float v = emb[(size_t)j * DIM + k];
  unsigned u = __float_as_uint(v);
  unsigned uh = u + 0x7FFFu + ((u >> 16) & 1u);
  unsigned short h = (unsigned short)(uh >> 16);
  float hf = __uint_as_float((unsigned)h << 16);
  float r = v - hf;                       // exact (Sterbenz)
  unsigned ur = __float_as_uint(r);
  unsigned ul = ur + 0x7FFFu + ((ur >> 16) & 1u);
  ebuf[(size_t)j * 512 + k]       = (short)h;
  ebuf[(size_t)j * 512 + 256 + k] = (short)(ul >> 16);
}

// ---------- P1: bf16-split MFMA distance filter -> 128j-block minima ----------
// 512 blocks x 256 thr (4 waves). Wave w: rows [nb + (w>>1)*32, +32),
// j-half (w&1)*2048. A-frags (z1,z2; 32 rows x 256 k) resident in VGPRs.
// B-frags straight from global ebuf (no LDS anywhere in this kernel).
// Layouts per m89/m118: A/B lane = [dim: lane&15][k: (lane>>4)*8 + i],
// C/D: col = lane&15, row = (lane>>4)*4 + reg.
__global__ __launch_bounds__(256, 2) void mfma_filter_kernel(
    const float* __restrict__ z, const short* __restrict__ ebuf,
    const float* __restrict__ E, float* __restrict__ minima) {
  const int t = threadIdx.x;
  const int w = t >> 6, lane = t & 63;
  const int quad = lane >> 4, l16 = lane & 15;
  const int jhalf = w & 1, rgrp = w >> 1;
  const int nb = blockIdx.x * 64;
  const int b = nb >> 10, hwb = nb & 1023;

  // ---- one-time: load + split A into registers ----
  bf16x8 a1[2][8], a2[2][8];
  const float* zb = z + (size_t)b * (DIM * HW_) + hwb + rgrp * 32 + l16;
#pragma unroll
  for (int mt = 0; mt < 2; ++mt) {
    const float* zp = zb + mt * 16;
#pragma unroll
    for (int ks = 0; ks < 8; ++ks) {
#pragma unroll
      for (int i = 0; i < 8; ++i) {
        float v = zp[(size_t)(ks * 32 + quad * 8 + i) * HW_];
        unsigned u = __float_as_uint(v);
        unsigned uh = u + 0x7FFFu + ((u >> 16) & 1u);
        unsigned short h = (unsigned short)(uh >> 16);
        float hf = __uint_as_float((unsigned)h << 16);
        float rres = v - hf;              // exact
        unsigned ur = __float_as_uint(rres);
        unsigned ul = ur + 0x7FFFu + ((ur >> 16) & 1u);
        a1[mt][ks][i] = (short)h;
        a2[mt][ks][i] = (short)(ul >> 16);
      }
    }
  }

  const f32x4 zero = {0.0f, 0.0f, 0.0f, 0.0f};
  for (int g128 = 0; g128 < 16; ++g128) {
    float runmin[2][4];
#pragma unroll
    for (int mt = 0; mt < 2; ++mt)
#pragma unroll
      for (int rg = 0; rg < 4; ++rg) runmin[mt][rg] = 3.0e38f;

    for (int h64 = 0; h64 < 2; ++h64) {
      const int jb = jhalf * 2048 + g128 * 128 + h64 * 64;
      f32x4 acc[4][2];
#pragma unroll
      for (int jt = 0; jt < 4; ++jt)
#pragma unroll
        for (int mt = 0; mt < 2; ++mt) acc[jt][mt] = zero;

#pragma unroll
      for (int ks = 0; ks < 8; ++ks) {
        bf16x8 b1[4], b2[4];
#pragma unroll
        for (int jt = 0; jt < 4; ++jt) {
          const short* p = ebuf + (size_t)(jb + jt * 16 + l16) * 512
                         + ks * 32 + quad * 8;
          b1[jt] = *(const bf16x8*)p;
          b2[jt] = *(const bf16x8*)(p + 256);
        }
#pragma unroll
        for (int jt = 0; jt < 4; ++jt)
#pragma unroll
          for (int mt = 0; mt < 2; ++mt) {
            acc[jt][mt] = __builtin_amdgcn_mfma_f32_16x16x32_bf16(
                a1[mt][ks], b1[jt], acc[jt][mt], 0, 0, 0);
            acc[jt][mt] = __builtin_amdgcn_mfma_f32_16x16x32_bf16(
                a1[mt][ks], b2[jt], acc[jt][mt], 0, 0, 0);
            acc[jt][mt] = __builtin_amdgcn_mfma_f32_16x16x32_bf16(
                a2[mt][ks], b1[jt], acc[jt][mt], 0, 0, 0);
          }
      }

      // epilogue: g = E_j - 2*M ; min over the 64 j's of this group
#pragma unroll
      for (int mt = 0; mt < 2; ++mt) {
#pragma unroll
        for (int rg = 0; rg < 4; ++rg) {
          float m = 3.0e38f;
#pragma unroll
          for (int jt = 0; jt < 4; ++jt) {
            float Ej = E[jb + jt * 16 + l16];
            float g = fmaf(-2.0f, acc[jt][mt][rg], Ej);
            m = fminf(m, g);
          }
#pragma unroll
          for (int mask = 1; mask <= 8; mask <<= 1)
            m = fminf(m, __shfl_xor(m, mask, 64));
          runmin[mt][rg] = fminf(runmin[mt][rg], m);
        }
      }
    }
    if (l16 == 0) {
#pragma unroll
      for (int mt = 0; mt < 2; ++mt)
#pragma unroll
        for (int rg = 0; rg < 4; ++rg) {
          int row = nb + rgrp * 32 + mt * 16 + quad * 4 + rg;
          minima[(size_t)row * 32 + jhalf * 16 + g128] = runmin[mt][rg];
        }
    }
  }
}

// ---------- P2: exact np-order rescue over qualifying 128j blocks ----------
#define P2PAD 260
__global__ __launch_bounds__(256) void exact_argmin_kernel(
    const float* __restrict__ z, const float* __restrict__ emb,
    const float* __restrict__ S, const float* __restrict__ E,
    const float* __restrict__ minima, int* __restrict__ idx_out,
    float* __restrict__ idxf_out) {
  __shared__ float ztr[64 * P2PAD];     // row-major z rows, padded
  const int t = threadIdx.x;
  const int nb = blockIdx.x * 64;
  const int b = nb >> 10, hwb = nb & 1023;
  const float* zb = z + (size_t)b * (DIM * HW_) + hwb;
#pragma unroll
  for (int i = 0; i < 16; ++i) {
    int slot = i * 256 + t;
    int k = slot >> 4, r4 = slot & 15;
    float4 v = *(const float4*)(zb + (size_t)k * HW_ + r4 * 4);
    ztr[(r4 * 4 + 0) * P2PAD + k] = v.x;
    ztr[(r4 * 4 + 1) * P2PAD + k] = v.y;
    ztr[(r4 * 4 + 2) * P2PAD + k] = v.z;
    ztr[(r4 * 4 + 3) * P2PAD + k] = v.w;
  }
  __syncthreads();
  const int w = t >> 6, lane = t & 63;
  for (int rr = 0; rr < 16; ++rr) {
    const int lr = w * 16 + rr;
    const int row = nb + lr;
    const float s = S[row];
    float bm = (lane < 32) ? minima[(size_t)row * 32 + lane] : 3.0e38f;
    float rm = bm;
#pragma unroll
    for (int mask = 1; mask <= 32; mask <<= 1)
      rm = fminf(rm, __shfl_xor(rm, mask, 64));
    bool ok = (lane < 32) && (bm <= rm + FILTER_T);
    unsigned long long mb = __ballot(ok);
    float bd = 3.0e38f; int bj = 0x7fffffff;
    const float* zr = &ztr[lr * P2PAD];
    while (mb) {
      int blk = __ffsll(mb) - 1;
      mb &= (mb - 1);
      int j1 = blk * 128 + lane, j2 = j1 + 64;
      const float* e1 = emb + (size_t)j1 * DIM;
      const float* e2 = emb + (size_t)j2 * DIM;
      float acc1 = 0.0f, acc2 = 0.0f;
      for (int k4 = 0; k4 < 64; ++k4) {      // sequential k ascending (np)
        float4 zv = *(const float4*)(zr + k4 * 4);
        float4 ea = *(const float4*)(e1 + k4 * 4);
        float4 eb = *(const float4*)(e2 + k4 * 4);
        acc1 = fmaf(zv.x, ea.x, acc1); acc1 = fmaf(zv.y, ea.y, acc1);
        acc1 = fmaf(zv.z, ea.z, acc1); acc1 = fmaf(zv.w, ea.w, acc1);
        acc2 = fmaf(zv.x, eb.x, acc2); acc2 = fmaf(zv.y, eb.y, acc2);
        acc2 = fmaf(zv.z, eb.z, acc2); acc2 = fmaf(zv.w, eb.w, acc2);
      }
      float d1 = fmaf(-2.0f, acc1, s + E[j1]);
      float d2 = fmaf(-2.0f, acc2, s + E[j2]);
      float dl; int jl;
      if (d2 < d1) { dl = d2; jl = j2; } else { dl = d1; jl = j1; }
      if (dl < bd || (dl == bd && jl < bj)) { bd = dl; bj = jl; }
    }
#pragma unroll
    for (int mask = 1; mask <= 32; mask <<= 1) {
      float od = __shfl_xor(bd, mask, 64);
      int   oj = __shfl_xor(bj, mask, 64);
      if (od < bd || (od == bd && oj < bj)) { bd = od; bj = oj; }
    }
    if (lane == 0) { idx_out[row] = bj; idxf_out[row] = (float)bj; }
  }
}

// ---------- fallback fp32 kernel (R2 version, known-passing) ----------
#define RT 64
#define JT 256
#define KC 16
__global__ __launch_bounds__(256, 2) void dist_argmin_kernel(
    const float* __restrict__ z, const float* __restrict__ emb,
    const float* __restrict__ S, const float* __restrict__ E,
    int* __restrict__ idx_out, float* __restrict__ idxf_out) {
  __shared__ float zt[DIM * RT];
  __shared__ float et[KC * JT];
  const int t  = threadIdx.x;
  const int g  = t & 31;
  const int tr = t >> 5;
  const int nb = blockIdx.x * RT;
  const int b  = nb >> 10;
  const int hwb = nb & 1023;
  const float* zb = z + (size_t)b * (DIM * HW_) + hwb;
#pragma unroll
  for (int i = 0; i < 16; ++i) {
    int flat = t + i * 256;
    int k  = flat >> 4;
    int r4 = flat & 15;
    float4 v = *(const float4*)(zb + (size_t)k * HW_ + r4 * 4);
    *(float4*)(zt + flat * 4) = v;
  }
  float bestd[8];
  int   bestj[8];
#pragma unroll
  for (int i = 0; i < 8; ++i) { bestd[i] = 3.0e38f; bestj[i] = 0; }
  float Sreg[8];
#pragma unroll
  for (int rr = 0; rr < 8; ++rr) Sreg[rr] = S[nb + tr * 8 + rr];
  float4 pf[4];
#pragma unroll
  for (int q = 0; q < 4; ++q) {
    int cid = q * 256 + t;
    pf[q] = *(const float4*)(emb + (size_t)(cid >> 2) * DIM + (cid & 3) * 4);
  }
  for (int jt = 0; jt < KEMB / JT; ++jt) {
    float acc[8][8];
#pragma unroll
    for (int rr = 0; rr < 8; ++rr)
#pragma unroll
      for (int c = 0; c < 8; ++c) acc[rr][c] = 0.0f;
    for (int kc = 0; kc < DIM / KC; ++kc) {
      __syncthreads();
#pragma unroll
      for (int q = 0; q < 4; ++q) {
        int cid = q * 256 + t;
        int j = cid >> 2, k4 = cid & 3;
        et[(k4 * 4 + 0) * JT + j] = pf[q].x;
        et[(k4 * 4 + 1) * JT + j] = pf[q].y;
        et[(k4 * 4 + 2) * JT + j] = pf[q].z;
        et[(k4 * 4 + 3) * JT + j] = pf[q].w;
      }
      int s = jt * (DIM / KC) + kc + 1;
      if (s < (KEMB / JT) * (DIM / KC)) {
        int njt = s >> 4, nkc = s & 15;
        const float* base = emb + (size_t)njt * JT * DIM + nkc * KC;
#pragma unroll
        for (int q = 0; q < 4; ++q) {
          int cid = q * 256 + t;
          pf[q] = *(const float4*)(base + (size_t)(cid >> 2) * DIM + (cid & 3) * 4);
        }
      }
      __syncthreads();
      const float* ztk = zt + (kc * KC) * RT;
#pragma unroll
      for (int kk = 0; kk < KC; ++kk) {
        float4 z0 = *(const float4*)(ztk + kk * RT + tr * 8);
        float4 z1 = *(const float4*)(ztk + kk * RT + tr * 8 + 4);
        float2 e0 = *(const float2*)(et + kk * JT + g * 2);
        float2 e1 = *(const float2*)(et + kk * JT + 64 + g * 2);
        float2 e2 = *(const float2*)(et + kk * JT + 128 + g * 2);
        float2 e3 = *(const float2*)(et + kk * JT + 192 + g * 2);
        float zr[8] = {z0.x, z0.y, z0.z, z0.w, z1.x, z1.y, z1.z, z1.w};
        float ev[8] = {e0.x, e0.y, e1.x, e1.y, e2.x, e2.y, e3.x, e3.y};
#pragma unroll
        for (int rr = 0; rr < 8; ++rr)
#pragma unroll
          for (int c = 0; c < 8; ++c)
            acc[rr][c] = fmaf(zr[rr], ev[c], acc[rr][c]);
      }
    }
    int jb = jt * JT;
    float Ereg[8];
#pragma unroll
    for (int c = 0; c < 8; ++c)
      Ereg[c] = E[jb + (c >> 1) * 64 + g * 2 + (c & 1)];
#pragma unroll
    for (int rr = 0; rr < 8; ++rr)
#pragma unroll
      for (int c = 0; c < 8; ++c) {
        float A = Sreg[rr] + Ereg[c];
        float d = fmaf(-2.0f, acc[rr][c], A);
        int j = jb + (c >> 1) * 64 + g * 2 + (c & 1);
        if (d < bestd[rr] || (d == bestd[rr] && j < bestj[rr])) {
          bestd[rr] = d; bestj[rr] = j;
        }
      }
  }
  __syncthreads();
  float* rd = et;
  int*   rj = (int*)(et + 2048);
#pragma unroll
  for (int rr = 0; rr < 8; ++rr) {
    rd[(tr * 8 + rr) * 32 + g] = bestd[rr];
    rj[(tr * 8 + rr) * 32 + g] = bestj[rr];
  }
  __syncthreads();
  if (t < RT) {
    float bd = rd[t * 32];
    int   bj = rj[t * 32];
    for (int c = 1; c < 32; ++c) {
      float d2 = rd[t * 32 + c];
      int   j2 = rj[t * 32 + c];
      if (d2 < bd || (d2 == bd && j2 < bj)) { bd = d2; bj = j2; }
    }
    idx_out[nb + t]  = bj;
    idxf_out[nb + t] = (float)bj;
  }
}

// ---------- K3: gather + STE output + loss partials ----------
__global__ __launch_bounds__(256) void epilogue_kernel(
    const float* __restrict__ z, const float* __restrict__ emb,
    const int* __restrict__ idx, float* __restrict__ out0,
    double* __restrict__ loss_sum) {
#pragma clang fp contract(off)
  __shared__ double wsum[4];
  double acc = 0.0;
#pragma unroll
  for (int it = 0; it < 4; ++it) {
    int u = (it * 2048 + blockIdx.x) * 256 + threadIdx.x;
    int gid = u * 4;
    int hw = gid & 1023;
    int d  = (gid >> 10) & 255;
    int b  = gid >> 18;
    int n  = b * 1024 + hw;
    float4 zp = *(const float4*)(z + gid);
    int4 iv = *(const int4*)(idx + n);
    float q0 = emb[(size_t)iv.x * DIM + d];
    float q1 = emb[(size_t)iv.y * DIM + d];
    float q2 = emb[(size_t)iv.z * DIM + d];
    float q3 = emb[(size_t)iv.w * DIM + d];
    float t0 = q0 - zp.x, t1 = q1 - zp.y, t2 = q2 - zp.z, t3 = q3 - zp.w;
    float4 o; o.x = zp.x + t0; o.y = zp.y + t1; o.z = zp.z + t2; o.w = zp.w + t3;
    *(float4*)(out0 + gid) = o;
    acc += (double)(t0 * t0);
    acc += (double)(t1 * t1);
    acc += (double)(t2 * t2);
    acc += (double)(t3 * t3);
  }
#pragma unroll
  for (int off = 32; off > 0; off >>= 1) acc += __shfl_down(acc, off, 64);
  int lane = threadIdx.x & 63, wv = threadIdx.x >> 6;
  if (lane == 0) wsum[wv] = acc;
  __syncthreads();
  if (threadIdx.x == 0) {
    double bsum = (wsum[0] + wsum[1]) + (wsum[2] + wsum[3]);
    atomicAdd(loss_sum, bsum);
  }
}

// ---------- K4: finalize loss ----------
__global__ void finalize_loss(const double* __restrict__ loss_sum,
                              float* __restrict__ out_loss) {
  double m = loss_sum[0] / 8388608.0;
  float mf = (float)m;
  float bb = 10.0f * mf;
  out_loss[0] = mf + bb;
}

extern "C" void kernel_launch(void* const* d_in, const int* in_sizes, int n_in,
                              void* d_out, int out_size, void* d_ws, size_t ws_size,
                              hipStream_t stream) {
  const float* z   = (const float*)d_in[0];
  const float* emb = (const float*)d_in[1];
  float* out = (float*)d_out;
  char* ws = (char*)d_ws;
  int*    idx = (int*)ws;
  float*  S   = (float*)(ws + WS_S_OFF);
  float*  E   = (float*)(ws + WS_E_OFF);
  double* ls  = (double*)(ws + WS_LOSS_OFF);

  hipMemsetAsync(ls, 0, sizeof(double), stream);
  norms_kernel<<<144, 256, 0, stream>>>(z, emb, S, E);

  if (ws_size >= (size_t)WS_NEEDED) {
    short* ebuf   = (short*)(ws + WS_EBUF_OFF);
    float* minima = (float*)(ws + WS_MIN_OFF);
    pack_e_kernel<<<KEMB, 256, 0, stream>>>(emb, ebuf);
    mfma_filter_kernel<<<512, 256, 0, stream>>>(z, ebuf, E, minima);
    exact_argmin_kernel<<<512, 256, 0, stream>>>(z, emb, S, E, minima, idx,
                                                 out + 8388609);
  } else {
    dist_argmin_kernel<<<NROWS / RT, 256, 0, stream>>>(z, emb, S, E, idx,
                                                       out + 8388609);
  }

  epilogue_kernel<<<2048, 256, 0, stream>>>(z, emb, idx, out, ls);
  finalize_loss<<<1, 1, 0, stream>>>(ls, out + 8388608);
}

// Round 4
// 663.497 us; speedup vs baseline: 2.7462x; 2.7462x over previous
//
#include <hip/hip_runtime.h>

#define DIM   256
#define HW_   1024
#define NROWS 32768
#define KEMB  4096

// ---------------- ws layout ----------------
// [0,      131072)   int    idx[32768]
// [131072, 262144)   float  S[32768]
// [262144, 278528)   float  E[4096]
// [278528, 278536)   double loss_sum
// [294912, 4489216)  R1: ebuf bf16-frag (2 MB, filter) then embT fp32 (4 MB, rescue)
// [4489216,8683520)  u16 minima[32768*64]  (bf16 per-row per-64j-group min)
#define WS_S_OFF    131072
#define WS_E_OFF    262144
#define WS_LOSS_OFF 278528
#define WS_R1_OFF   294912
#define WS_MIN_OFF  4489216
#define WS_NEEDED   8683520
#define RESCUE_W    1.5e-4f

typedef __attribute__((ext_vector_type(8))) short bf16x8;
typedef __attribute__((ext_vector_type(4))) float f32x4;

__device__ __forceinline__ unsigned short f2bf(float v) {
  unsigned u = __float_as_uint(v);
  return (unsigned short)((u + 0x7FFFu + ((u >> 16) & 1u)) >> 16);
}

// ---------- K1: numpy-pairwise row sums of squares ----------
__device__ __forceinline__ float np_sumsq_128(const float* q, int stride) {
#pragma clang fp contract(off)
  float r[8];
#pragma unroll
  for (int i = 0; i < 8; ++i) { float v = q[i * stride]; r[i] = v * v; }
  for (int blk = 8; blk < 128; blk += 8) {
#pragma unroll
    for (int i = 0; i < 8; ++i) {
      float v = q[(blk + i) * stride];
      float sq = v * v;
      r[i] = r[i] + sq;
    }
  }
  return ((r[0] + r[1]) + (r[2] + r[3])) + ((r[4] + r[5]) + (r[6] + r[7]));
}

__global__ __launch_bounds__(256) void norms_kernel(
    const float* __restrict__ z, const float* __restrict__ emb,
    float* __restrict__ S, float* __restrict__ E) {
#pragma clang fp contract(off)
  int t = blockIdx.x * 256 + threadIdx.x;
  if (t < NROWS) {
    int b = t >> 10, hw = t & 1023;
    const float* p = z + (size_t)b * (DIM * HW_) + hw;
    float s0 = np_sumsq_128(p, HW_);
    float s1 = np_sumsq_128(p + 128 * HW_, HW_);
    S[t] = s0 + s1;
  } else if (t < NROWS + KEMB) {
    int j = t - NROWS;
    const float* p = emb + (size_t)j * DIM;
    float s0 = np_sumsq_128(p, 1);
    float s1 = np_sumsq_128(p + 128, 1);
    E[j] = s0 + s1;
  }
}

// ---------- pack1: emb -> bf16 fragment-major ebuf ----------
// tile (g16, ks): 64 lanes x 8 shorts; lane l holds e[j = g16*16 + (l&15)]
// [k = ks*32 + (l>>4)*8 + i].  Tile = 1 KB contiguous -> filter B-loads coalesce.
__global__ __launch_bounds__(256) void pack_e_kernel(
    const float* __restrict__ emb, short* __restrict__ ebuf) {
  int u = blockIdx.x * 256 + threadIdx.x;      // 131072 threads
  int lane = u & 63;
  int ks = (u >> 6) & 7;
  int g16 = u >> 9;
  int j = g16 * 16 + (lane & 15);
  int kb = ks * 32 + (lane >> 4) * 8;
  const float* p = emb + (size_t)j * DIM + kb;
  short out[8];
#pragma unroll
  for (int i = 0; i < 8; ++i) out[i] = (short)f2bf(p[i]);
  *(bf16x8*)(ebuf + (size_t)u * 8) = *(bf16x8*)out;
}

// ---------- pack2: emb -> k-major fp32 embT (for rescue) ----------
__global__ __launch_bounds__(256) void pack_et_kernel(
    const float* __restrict__ emb, float* __restrict__ embT) {
  int u = blockIdx.x * 256 + threadIdx.x;      // 1048576 threads
  int j = u & 4095;
  int k = u >> 12;
  embT[(size_t)k * KEMB + j] = emb[(size_t)j * DIM + k];
}

// ---------- P1: single-pass bf16 MFMA filter -> 64j-group minima (bf16) ----------
// 512 blocks x 4 waves. Wave w: rgrp = w>>1 (rows +32), jhalf = w&1 (2048 j).
// A-frags (32 rows x 256 k) resident in VGPRs; B-frags coalesced from ebuf.
// Layout HW-verified in R3 (absmax 0): A/B lane=[m: lane&15][k:(lane>>4)*8+i],
// C/D: col=lane&15, row=(lane>>4)*4+reg.
__global__ __launch_bounds__(256, 2) void mfma_filter_kernel(
    const float* __restrict__ z, const short* __restrict__ ebuf,
    const float* __restrict__ E, unsigned short* __restrict__ minima) {
  const int t = threadIdx.x;
  const int w = t >> 6, lane = t & 63;
  const int quad = lane >> 4, l16 = lane & 15;
  const int jhalf = w & 1, rgrp = w >> 1;
  const int nb = blockIdx.x * 64;
  const int b = nb >> 10, hwb = nb & 1023;

  // one-time A load + bf16 convert
  bf16x8 a[2][8];
  const float* zb = z + (size_t)b * (DIM * HW_) + hwb + rgrp * 32 + l16;
#pragma unroll
  for (int mt = 0; mt < 2; ++mt) {
    const float* zp = zb + mt * 16;
#pragma unroll
    for (int ks = 0; ks < 8; ++ks) {
      short tmp[8];
#pragma unroll
      for (int i = 0; i < 8; ++i)
        tmp[i] = (short)f2bf(zp[(size_t)(ks * 32 + quad * 8 + i) * HW_]);
      a[mt][ks] = *(bf16x8*)tmp;
    }
  }

  const f32x4 zero = {0.0f, 0.0f, 0.0f, 0.0f};
  for (int g128 = 0; g128 < 16; ++g128) {
#pragma unroll
    for (int h64 = 0; h64 < 2; ++h64) {
      const int jb = jhalf * 2048 + g128 * 128 + h64 * 64;
      const int g16b = jb >> 4;
      f32x4 acc[4][2];
#pragma unroll
      for (int jt = 0; jt < 4; ++jt)
#pragma unroll
        for (int mt = 0; mt < 2; ++mt) acc[jt][mt] = zero;

#pragma unroll
      for (int ks = 0; ks < 8; ++ks) {
        bf16x8 bfr[4];
#pragma unroll
        for (int jt = 0; jt < 4; ++jt)
          bfr[jt] = *(const bf16x8*)(ebuf +
              ((size_t)(g16b + jt) * 8 + ks) * 512 + lane * 8);
#pragma unroll
        for (int jt = 0; jt < 4; ++jt)
#pragma unroll
          for (int mt = 0; mt < 2; ++mt)
            acc[jt][mt] = __builtin_amdgcn_mfma_f32_16x16x32_bf16(
                a[mt][ks], bfr[jt], acc[jt][mt], 0, 0, 0);
      }

      // epilogue: g = E_j - 2M ; group(64j)-min per row -> bf16 store
      float Ej[4];
#pragma unroll
      for (int jt = 0; jt < 4; ++jt) Ej[jt] = E[jb + jt * 16 + l16];
#pragma unroll
      for (int mt = 0; mt < 2; ++mt) {
#pragma unroll
        for (int rg = 0; rg < 4; ++rg) {
          float m = 3.0e38f;
#pragma unroll
          for (int jt = 0; jt < 4; ++jt)
            m = fminf(m, fmaf(-2.0f, acc[jt][mt][rg], Ej[jt]));
#pragma unroll
          for (int mask = 1; mask <= 8; mask <<= 1)
            m = fminf(m, __shfl_xor(m, mask, 64));
          if (l16 == 0) {
            int row = nb + rgrp * 32 + mt * 16 + quad * 4 + rg;
            minima[(size_t)row * 64 + (jb >> 6)] = f2bf(m);
          }
        }
      }
    }
  }
}

// ---------- P2: exact np-order rescue over qualifying 64j groups ----------
// Block = 64 rows (z staged to LDS); wave w handles rows w*16..+15.
// Per candidate group: lane -> j = g*64+lane; e from k-major embT (coalesced
// 256B/step); z[k] broadcast from LDS; sequential-k fp32 FMA chain (np order).
#define P2PAD 257
__global__ __launch_bounds__(256) void exact_argmin_kernel(
    const float* __restrict__ z, const float* __restrict__ embT,
    const float* __restrict__ S, const float* __restrict__ E,
    const unsigned short* __restrict__ minima, int* __restrict__ idx_out,
    float* __restrict__ idxf_out) {
  __shared__ float ztr[64 * P2PAD];
  const int t = threadIdx.x;
  const int nb = blockIdx.x * 64;
  const int b = nb >> 10, hwb = nb & 1023;
  const float* zb = z + (size_t)b * (DIM * HW_) + hwb;
#pragma unroll
  for (int i = 0; i < 16; ++i) {
    int slot = i * 256 + t;
    int k = slot >> 4, r4 = slot & 15;
    float4 v = *(const float4*)(zb + (size_t)k * HW_ + r4 * 4);
    ztr[(r4 * 4 + 0) * P2PAD + k] = v.x;
    ztr[(r4 * 4 + 1) * P2PAD + k] = v.y;
    ztr[(r4 * 4 + 2) * P2PAD + k] = v.z;
    ztr[(r4 * 4 + 3) * P2PAD + k] = v.w;
  }
  __syncthreads();
  const int w = t >> 6, lane = t & 63;
  for (int rr = 0; rr < 16; ++rr) {
    const int lr = w * 16 + rr;
    const int row = nb + lr;
    float m = __uint_as_float((unsigned)minima[(size_t)row * 64 + lane] << 16);
    float gm = m;
#pragma unroll
    for (int mask = 1; mask <= 32; mask <<= 1)
      gm = fminf(gm, __shfl_xor(gm, mask, 64));
    unsigned long long mb = __ballot(m <= gm + RESCUE_W);
    const float s = S[row];
    float bd = 3.0e38f; int bj = 0x7fffffff;
    const float* zr = &ztr[lr * P2PAD];
    while (mb) {
      int g = __ffsll(mb) - 1;
      mb &= (mb - 1);
      int j = g * 64 + lane;
      const float* ep = embT + j;
      float acc = 0.0f;
#pragma unroll 8
      for (int k = 0; k < DIM; ++k)
        acc = fmaf(zr[k], ep[(size_t)k * KEMB], acc);
      float d = fmaf(-2.0f, acc, s + E[j]);
      if (d < bd || (d == bd && j < bj)) { bd = d; bj = j; }
    }
#pragma unroll
    for (int mask = 1; mask <= 32; mask <<= 1) {
      float od = __shfl_xor(bd, mask, 64);
      int   oj = __shfl_xor(bj, mask, 64);
      if (od < bd || (od == bd && oj < bj)) { bd = od; bj = oj; }
    }
    if (lane == 0) { idx_out[row] = bj; idxf_out[row] = (float)bj; }
  }
}

// ---------- fallback fp32 kernel (R2 version, known-passing) ----------
#define RT 64
#define JT 256
#define KC 16
__global__ __launch_bounds__(256, 2) void dist_argmin_kernel(
    const float* __restrict__ z, const float* __restrict__ emb,
    const float* __restrict__ S, const float* __restrict__ E,
    int* __restrict__ idx_out, float* __restrict__ idxf_out) {
  __shared__ float zt[DIM * RT];
  __shared__ float et[KC * JT];
  const int t  = threadIdx.x;
  const int g  = t & 31;
  const int tr = t >> 5;
  const int nb = blockIdx.x * RT;
  const int b  = nb >> 10;
  const int hwb = nb & 1023;
  const float* zb = z + (size_t)b * (DIM * HW_) + hwb;
#pragma unroll
  for (int i = 0; i < 16; ++i) {
    int flat = t + i * 256;
    int k  = flat >> 4;
    int r4 = flat & 15;
    float4 v = *(const float4*)(zb + (size_t)k * HW_ + r4 * 4);
    *(float4*)(zt + flat * 4) = v;
  }
  float bestd[8];
  int   bestj[8];
#pragma unroll
  for (int i = 0; i < 8; ++i) { bestd[i] = 3.0e38f; bestj[i] = 0; }
  float Sreg[8];
#pragma unroll
  for (int rr = 0; rr < 8; ++rr) Sreg[rr] = S[nb + tr * 8 + rr];
  float4 pf[4];
#pragma unroll
  for (int q = 0; q < 4; ++q) {
    int cid = q * 256 + t;
    pf[q] = *(const float4*)(emb + (size_t)(cid >> 2) * DIM + (cid & 3) * 4);
  }
  for (int jt = 0; jt < KEMB / JT; ++jt) {
    float acc[8][8];
#pragma unroll
    for (int rr = 0; rr < 8; ++rr)
#pragma unroll
      for (int c = 0; c < 8; ++c) acc[rr][c] = 0.0f;
    for (int kc = 0; kc < DIM / KC; ++kc) {
      __syncthreads();
#pragma unroll
      for (int q = 0; q < 4; ++q) {
        int cid = q * 256 + t;
        int j = cid >> 2, k4 = cid & 3;
        et[(k4 * 4 + 0) * JT + j] = pf[q].x;
        et[(k4 * 4 + 1) * JT + j] = pf[q].y;
        et[(k4 * 4 + 2) * JT + j] = pf[q].z;
        et[(k4 * 4 + 3) * JT + j] = pf[q].w;
      }
      int s = jt * (DIM / KC) + kc + 1;
      if (s < (KEMB / JT) * (DIM / KC)) {
        int njt = s >> 4, nkc = s & 15;
        const float* base = emb + (size_t)njt * JT * DIM + nkc * KC;
#pragma unroll
        for (int q = 0; q < 4; ++q) {
          int cid = q * 256 + t;
          pf[q] = *(const float4*)(base + (size_t)(cid >> 2) * DIM + (cid & 3) * 4);
        }
      }
      __syncthreads();
      const float* ztk = zt + (kc * KC) * RT;
#pragma unroll
      for (int kk = 0; kk < KC; ++kk) {
        float4 z0 = *(const float4*)(ztk + kk * RT + tr * 8);
        float4 z1 = *(const float4*)(ztk + kk * RT + tr * 8 + 4);
        float2 e0 = *(const float2*)(et + kk * JT + g * 2);
        float2 e1 = *(const float2*)(et + kk * JT + 64 + g * 2);
        float2 e2 = *(const float2*)(et + kk * JT + 128 + g * 2);
        float2 e3 = *(const float2*)(et + kk * JT + 192 + g * 2);
        float zr[8] = {z0.x, z0.y, z0.z, z0.w, z1.x, z1.y, z1.z, z1.w};
        float ev[8] = {e0.x, e0.y, e1.x, e1.y, e2.x, e2.y, e3.x, e3.y};
#pragma unroll
        for (int rr = 0; rr < 8; ++rr)
#pragma unroll
          for (int c = 0; c < 8; ++c)
            acc[rr][c] = fmaf(zr[rr], ev[c], acc[rr][c]);
      }
    }
    int jb = jt * JT;
    float Ereg[8];
#pragma unroll
    for (int c = 0; c < 8; ++c)
      Ereg[c] = E[jb + (c >> 1) * 64 + g * 2 + (c & 1)];
#pragma unroll
    for (int rr = 0; rr < 8; ++rr)
#pragma unroll
      for (int c = 0; c < 8; ++c) {
        float A = Sreg[rr] + Ereg[c];
        float d = fmaf(-2.0f, acc[rr][c], A);
        int j = jb + (c >> 1) * 64 + g * 2 + (c & 1);
        if (d < bestd[rr] || (d == bestd[rr] && j < bestj[rr])) {
          bestd[rr] = d; bestj[rr] = j;
        }
      }
  }
  __syncthreads();
  float* rd = et;
  int*   rj = (int*)(et + 2048);
#pragma unroll
  for (int rr = 0; rr < 8; ++rr) {
    rd[(tr * 8 + rr) * 32 + g] = bestd[rr];
    rj[(tr * 8 + rr) * 32 + g] = bestj[rr];
  }
  __syncthreads();
  if (t < RT) {
    float bd = rd[t * 32];
    int   bj = rj[t * 32];
    for (int c = 1; c < 32; ++c) {
      float d2 = rd[t * 32 + c];
      int   j2 = rj[t * 32 + c];
      if (d2 < bd || (d2 == bd && j2 < bj)) { bd = d2; bj = j2; }
    }
    idx_out[nb + t]  = bj;
    idxf_out[nb + t] = (float)bj;
  }
}

// ---------- K3: gather + STE output + loss partials ----------
__global__ __launch_bounds__(256) void epilogue_kernel(
    const float* __restrict__ z, const float* __restrict__ emb,
    const int* __restrict__ idx, float* __restrict__ out0,
    double* __restrict__ loss_sum) {
#pragma clang fp contract(off)
  __shared__ double wsum[4];
  double acc = 0.0;
#pragma unroll
  for (int it = 0; it < 4; ++it) {
    int u = (it * 2048 + blockIdx.x) * 256 + threadIdx.x;
    int gid = u * 4;
    int hw = gid & 1023;
    int d  = (gid >> 10) & 255;
    int b  = gid >> 18;
    int n  = b * 1024 + hw;
    float4 zp = *(const float4*)(z + gid);
    int4 iv = *(const int4*)(idx + n);
    float q0 = emb[(size_t)iv.x * DIM + d];
    float q1 = emb[(size_t)iv.y * DIM + d];
    float q2 = emb[(size_t)iv.z * DIM + d];
    float q3 = emb[(size_t)iv.w * DIM + d];
    float t0 = q0 - zp.x, t1 = q1 - zp.y, t2 = q2 - zp.z, t3 = q3 - zp.w;
    float4 o; o.x = zp.x + t0; o.y = zp.y + t1; o.z = zp.z + t2; o.w = zp.w + t3;
    *(float4*)(out0 + gid) = o;
    acc += (double)(t0 * t0);
    acc += (double)(t1 * t1);
    acc += (double)(t2 * t2);
    acc += (double)(t3 * t3);
  }
#pragma unroll
  for (int off = 32; off > 0; off >>= 1) acc += __shfl_down(acc, off, 64);
  int lane = threadIdx.x & 63, wv = threadIdx.x >> 6;
  if (lane == 0) wsum[wv] = acc;
  __syncthreads();
  if (threadIdx.x == 0) {
    double bsum = (wsum[0] + wsum[1]) + (wsum[2] + wsum[3]);
    atomicAdd(loss_sum, bsum);
  }
}

// ---------- K4: finalize loss ----------
__global__ void finalize_loss(const double* __restrict__ loss_sum,
                              float* __restrict__ out_loss) {
  double m = loss_sum[0] / 8388608.0;
  float mf = (float)m;
  float bb = 10.0f * mf;
  out_loss[0] = mf + bb;
}

extern "C" void kernel_launch(void* const* d_in, const int* in_sizes, int n_in,
                              void* d_out, int out_size, void* d_ws, size_t ws_size,
                              hipStream_t stream) {
  const float* z   = (const float*)d_in[0];
  const float* emb = (const float*)d_in[1];
  float* out = (float*)d_out;
  char* ws = (char*)d_ws;
  int*    idx = (int*)ws;
  float*  S   = (float*)(ws + WS_S_OFF);
  float*  E   = (float*)(ws + WS_E_OFF);
  double* ls  = (double*)(ws + WS_LOSS_OFF);

  hipMemsetAsync(ls, 0, sizeof(double), stream);
  norms_kernel<<<144, 256, 0, stream>>>(z, emb, S, E);

  if (ws_size >= (size_t)WS_NEEDED) {
    short*          ebuf   = (short*)(ws + WS_R1_OFF);
    float*          embT   = (float*)(ws + WS_R1_OFF);
    unsigned short* minima = (unsigned short*)(ws + WS_MIN_OFF);
    pack_e_kernel<<<512, 256, 0, stream>>>(emb, ebuf);
    mfma_filter_kernel<<<512, 256, 0, stream>>>(z, ebuf, E, minima);
    pack_et_kernel<<<4096, 256, 0, stream>>>(emb, embT);   // overwrites ebuf (done)
    exact_argmin_kernel<<<512, 256, 0, stream>>>(z, embT, S, E, minima, idx,
                                                 out + 8388609);
  } else {
    dist_argmin_kernel<<<NROWS / RT, 256, 0, stream>>>(z, emb, S, E, idx,
                                                       out + 8388609);
  }

  epilogue_kernel<<<2048, 256, 0, stream>>>(z, emb, idx, out, ls);
  finalize_loss<<<1, 1, 0, stream>>>(ls, out + 8388608);
}

// Round 5
// 338.677 us; speedup vs baseline: 5.3801x; 1.9591x over previous
//
#include <hip/hip_runtime.h>

#define DIM   256
#define HW_   1024
#define NROWS 32768
#define KEMB  4096

// ---------------- ws layout ----------------
// [0,       131072)  int    idx[32768]
// [131072,  262144)  float  S[32768]
// [262144,  278528)  float  E[4096]
// [278528,  278536)  double loss_sum
// [278592,  409664)  int    cnt[32768]
// [409664,  1458240) int    cand[32768][8]
// [1458240, 5652544) short  ebuf[4096*512]  (bf16 fragment-major)
#define WS_S_OFF    131072
#define WS_E_OFF    262144
#define WS_LOSS_OFF 278528
#define WS_CNT_OFF  278592
#define WS_CAND_OFF 409664
#define WS_EBUF_OFF 1458240
#define WS_NEEDED   5652544
#define RESCUE_W    1.5e-4f

typedef __attribute__((ext_vector_type(8))) short bf16x8;
typedef __attribute__((ext_vector_type(4))) float f32x4;

__device__ __forceinline__ unsigned short f2bf(float v) {
  unsigned u = __float_as_uint(v);
  return (unsigned short)((u + 0x7FFFu + ((u >> 16) & 1u)) >> 16);
}

// ---------- K1: numpy-pairwise row sums of squares ----------
__device__ __forceinline__ float np_sumsq_128(const float* q, int stride) {
#pragma clang fp contract(off)
  float r[8];
#pragma unroll
  for (int i = 0; i < 8; ++i) { float v = q[i * stride]; r[i] = v * v; }
  for (int blk = 8; blk < 128; blk += 8) {
#pragma unroll
    for (int i = 0; i < 8; ++i) {
      float v = q[(blk + i) * stride];
      float sq = v * v;
      r[i] = r[i] + sq;
    }
  }
  return ((r[0] + r[1]) + (r[2] + r[3])) + ((r[4] + r[5]) + (r[6] + r[7]));
}

__global__ __launch_bounds__(256) void norms_kernel(
    const float* __restrict__ z, const float* __restrict__ emb,
    float* __restrict__ S, float* __restrict__ E) {
#pragma clang fp contract(off)
  int t = blockIdx.x * 256 + threadIdx.x;
  if (t < NROWS) {
    int b = t >> 10, hw = t & 1023;
    const float* p = z + (size_t)b * (DIM * HW_) + hw;
    float s0 = np_sumsq_128(p, HW_);
    float s1 = np_sumsq_128(p + 128 * HW_, HW_);
    S[t] = s0 + s1;
  } else if (t < NROWS + KEMB) {
    int j = t - NROWS;
    const float* p = emb + (size_t)j * DIM;
    float s0 = np_sumsq_128(p, 1);
    float s1 = np_sumsq_128(p + 128, 1);
    E[j] = s0 + s1;
  }
}

// ---------- pack: emb -> bf16 fragment-major ebuf ----------
// tile (g16, ks): 64 lanes x 8 shorts; lane l holds e[j = g16*16 + (l&15)]
// [k = ks*32 + (l>>4)*8 + i]. 1 KB contiguous per tile.
__global__ __launch_bounds__(256) void pack_e_kernel(
    const float* __restrict__ emb, short* __restrict__ ebuf) {
  int u = blockIdx.x * 256 + threadIdx.x;      // 131072 threads
  int lane = u & 63;
  int ks = (u >> 6) & 7;
  int g16 = u >> 9;
  int j = g16 * 16 + (lane & 15);
  int kb = ks * 32 + (lane >> 4) * 8;
  const float* p = emb + (size_t)j * DIM + kb;
  short out[8];
#pragma unroll
  for (int i = 0; i < 8; ++i) out[i] = (short)f2bf(p[i]);
  *(bf16x8*)(ebuf + (size_t)u * 8) = *(bf16x8*)out;
}

// ---------- filter v2: two-sweep bf16 MFMA -> per-j candidate lists ----------
// 512 blocks x 4 waves; block = 64 rows. Wave w = j-quarter [w*1024,+1024).
// mt=4: A (64 rows x 256 k bf16) resident in 128 VGPRs per wave.
// Sweep 0: exact fp32 row minima of g = E_j - 2*M_bf16.
// Sweep 1: identical MFMA recompute; emit j where g <= rowmin + W.
// Layouts HW-verified (R3/R4 absmax 0): A/B lane=[m:lane&15][k:(lane>>4)*8+i],
// C/D: col=lane&15, row=(lane>>4)*4+reg.
__global__ __launch_bounds__(256, 2) void filter2_kernel(
    const float* __restrict__ z, const short* __restrict__ ebuf,
    const float* __restrict__ E, int* __restrict__ cnt_g,
    int* __restrict__ cand_g) {
  __shared__ float rowmin_l[64][4];
  __shared__ float thr_l[64];
  __shared__ int   cnt_l[64];
  __shared__ int   cand_l[64][8];

  const int t = threadIdx.x;
  const int w = t >> 6, lane = t & 63;
  const int quad = lane >> 4, l16 = lane & 15;
  const int nb = blockIdx.x * 64;
  const int b = nb >> 10, hwb = nb & 1023;   // 64 | 1024: no b straddle

  // ---- one-time A load + bf16 convert (64 rows, mt=4) ----
  bf16x8 a[4][8];
  const float* zb = z + (size_t)b * (DIM * HW_) + hwb + l16;
#pragma unroll
  for (int mt = 0; mt < 4; ++mt) {
    const float* zp = zb + mt * 16;
#pragma unroll
    for (int ks = 0; ks < 8; ++ks) {
      short tmp[8];
#pragma unroll
      for (int i = 0; i < 8; ++i)
        tmp[i] = (short)f2bf(zp[(size_t)(ks * 32 + quad * 8 + i) * HW_]);
      a[mt][ks] = *(bf16x8*)tmp;
    }
  }

  const f32x4 zero = {0.0f, 0.0f, 0.0f, 0.0f};

  // ================= sweep 0: row minima =================
  float runmin[4][4];
#pragma unroll
  for (int mt = 0; mt < 4; ++mt)
#pragma unroll
    for (int rg = 0; rg < 4; ++rg) runmin[mt][rg] = 3.0e38f;

  for (int grp = 0; grp < 32; ++grp) {
    const int jb = w * 1024 + grp * 32;
    const int g16b = jb >> 4;
    f32x4 acc[2][4];
#pragma unroll
    for (int jt = 0; jt < 2; ++jt)
#pragma unroll
      for (int mt = 0; mt < 4; ++mt) acc[jt][mt] = zero;
#pragma unroll
    for (int ks = 0; ks < 8; ++ks) {
      bf16x8 bfr[2];
#pragma unroll
      for (int jt = 0; jt < 2; ++jt)
        bfr[jt] = *(const bf16x8*)(ebuf +
            ((size_t)(g16b + jt) * 8 + ks) * 512 + lane * 8);
#pragma unroll
      for (int jt = 0; jt < 2; ++jt)
#pragma unroll
        for (int mt = 0; mt < 4; ++mt)
          acc[jt][mt] = __builtin_amdgcn_mfma_f32_16x16x32_bf16(
              a[mt][ks], bfr[jt], acc[jt][mt], 0, 0, 0);
    }
#pragma unroll
    for (int jt = 0; jt < 2; ++jt) {
      float Ej = E[jb + jt * 16 + l16];
#pragma unroll
      for (int mt = 0; mt < 4; ++mt)
#pragma unroll
        for (int rg = 0; rg < 4; ++rg) {
          float g = fmaf(-2.0f, acc[jt][mt][rg], Ej);
          runmin[mt][rg] = fminf(runmin[mt][rg], g);
        }
    }
  }
  // reduce over the 16 j-columns (l16 lanes within each quad)
#pragma unroll
  for (int mt = 0; mt < 4; ++mt)
#pragma unroll
    for (int rg = 0; rg < 4; ++rg) {
      float m = runmin[mt][rg];
#pragma unroll
      for (int mask = 1; mask <= 8; mask <<= 1)
        m = fminf(m, __shfl_xor(m, mask, 64));
      runmin[mt][rg] = m;
    }
  if (l16 == 0) {
#pragma unroll
    for (int mt = 0; mt < 4; ++mt)
#pragma unroll
      for (int rg = 0; rg < 4; ++rg)
        rowmin_l[mt * 16 + quad * 4 + rg][w] = runmin[mt][rg];
  }
  __syncthreads();
  if (t < 64) {
    float m = fminf(fminf(rowmin_l[t][0], rowmin_l[t][1]),
                    fminf(rowmin_l[t][2], rowmin_l[t][3]));
    thr_l[t] = m + RESCUE_W;
    cnt_l[t] = 0;
  }
  __syncthreads();
  float thrv[4][4];
#pragma unroll
  for (int mt = 0; mt < 4; ++mt)
#pragma unroll
    for (int rg = 0; rg < 4; ++rg)
      thrv[mt][rg] = thr_l[mt * 16 + quad * 4 + rg];

  // ================= sweep 1: emission =================
  for (int grp = 0; grp < 32; ++grp) {
    const int jb = w * 1024 + grp * 32;
    const int g16b = jb >> 4;
    f32x4 acc[2][4];
#pragma unroll
    for (int jt = 0; jt < 2; ++jt)
#pragma unroll
      for (int mt = 0; mt < 4; ++mt) acc[jt][mt] = zero;
#pragma unroll
    for (int ks = 0; ks < 8; ++ks) {
      bf16x8 bfr[2];
#pragma unroll
      for (int jt = 0; jt < 2; ++jt)
        bfr[jt] = *(const bf16x8*)(ebuf +
            ((size_t)(g16b + jt) * 8 + ks) * 512 + lane * 8);
#pragma unroll
      for (int jt = 0; jt < 2; ++jt)
#pragma unroll
        for (int mt = 0; mt < 4; ++mt)
          acc[jt][mt] = __builtin_amdgcn_mfma_f32_16x16x32_bf16(
              a[mt][ks], bfr[jt], acc[jt][mt], 0, 0, 0);
    }
#pragma unroll
    for (int jt = 0; jt < 2; ++jt) {
      int jcol = jb + jt * 16 + l16;
      float Ej = E[jcol];
#pragma unroll
      for (int mt = 0; mt < 4; ++mt)
#pragma unroll
        for (int rg = 0; rg < 4; ++rg) {
          float g = fmaf(-2.0f, acc[jt][mt][rg], Ej);
          if (g <= thrv[mt][rg]) {
            int rl = mt * 16 + quad * 4 + rg;
            int slot = atomicAdd(&cnt_l[rl], 1);
            if (slot < 8) cand_l[rl][slot] = jcol;
          }
        }
    }
  }
  __syncthreads();
  if (t < 64) {
    int c = cnt_l[t];
    cnt_g[nb + t] = c;
    int cc = c > 8 ? 8 : c;
    for (int p = 0; p < cc; ++p) cand_g[(size_t)(nb + t) * 8 + p] = cand_l[t][p];
  }
}

// ---------- rescue v2: exact np-order chains over per-row candidates ----------
// One thread per row; consecutive lanes = consecutive rows -> z reads coalesce.
__global__ __launch_bounds__(256) void exact_cand_kernel(
    const float* __restrict__ z, const float* __restrict__ emb,
    const float* __restrict__ S, const float* __restrict__ E,
    const int* __restrict__ cnt_g, const int* __restrict__ cand_g,
    int* __restrict__ idx_out, float* __restrict__ idxf_out) {
  int row = blockIdx.x * 256 + threadIdx.x;
  int b = row >> 10, hw = row & 1023;
  const float* zr = z + (size_t)b * (DIM * HW_) + hw;   // z[k] at zr[k*1024]
  const float s = S[row];
  int c = cnt_g[row];
  float bd = 3.0e38f; int bj = 0x7fffffff;
  if (c <= 8) {
    for (int p = 0; p < c; ++p) {
      int j = cand_g[(size_t)row * 8 + p];
      const float* e = emb + (size_t)j * DIM;
      float acc = 0.0f;
#pragma unroll 8
      for (int k4 = 0; k4 < 64; ++k4) {          // sequential k ascending
        float4 ev = *(const float4*)(e + k4 * 4);
        acc = fmaf(zr[(size_t)(k4 * 4 + 0) * HW_], ev.x, acc);
        acc = fmaf(zr[(size_t)(k4 * 4 + 1) * HW_], ev.y, acc);
        acc = fmaf(zr[(size_t)(k4 * 4 + 2) * HW_], ev.z, acc);
        acc = fmaf(zr[(size_t)(k4 * 4 + 3) * HW_], ev.w, acc);
      }
      float d = fmaf(-2.0f, acc, s + E[j]);
      if (d < bd || (d == bd && j < bj)) { bd = d; bj = j; }
    }
  } else {
    // overflow (P ~ 0): exact full scan, still np-order correct
    for (int j = 0; j < KEMB; ++j) {
      const float* e = emb + (size_t)j * DIM;
      float acc = 0.0f;
      for (int k4 = 0; k4 < 64; ++k4) {
        float4 ev = *(const float4*)(e + k4 * 4);
        acc = fmaf(zr[(size_t)(k4 * 4 + 0) * HW_], ev.x, acc);
        acc = fmaf(zr[(size_t)(k4 * 4 + 1) * HW_], ev.y, acc);
        acc = fmaf(zr[(size_t)(k4 * 4 + 2) * HW_], ev.z, acc);
        acc = fmaf(zr[(size_t)(k4 * 4 + 3) * HW_], ev.w, acc);
      }
      float d = fmaf(-2.0f, acc, s + E[j]);
      if (d < bd || (d == bd && j < bj)) { bd = d; bj = j; }
    }
  }
  idx_out[row] = bj;
  idxf_out[row] = (float)bj;
}

// ---------- fallback fp32 kernel (R2 version, known-passing) ----------
#define RT 64
#define JT 256
#define KC 16
__global__ __launch_bounds__(256, 2) void dist_argmin_kernel(
    const float* __restrict__ z, const float* __restrict__ emb,
    const float* __restrict__ S, const float* __restrict__ E,
    int* __restrict__ idx_out, float* __restrict__ idxf_out) {
  __shared__ float zt[DIM * RT];
  __shared__ float et[KC * JT];
  const int t  = threadIdx.x;
  const int g  = t & 31;
  const int tr = t >> 5;
  const int nb = blockIdx.x * RT;
  const int b  = nb >> 10;
  const int hwb = nb & 1023;
  const float* zb = z + (size_t)b * (DIM * HW_) + hwb;
#pragma unroll
  for (int i = 0; i < 16; ++i) {
    int flat = t + i * 256;
    int k  = flat >> 4;
    int r4 = flat & 15;
    float4 v = *(const float4*)(zb + (size_t)k * HW_ + r4 * 4);
    *(float4*)(zt + flat * 4) = v;
  }
  float bestd[8];
  int   bestj[8];
#pragma unroll
  for (int i = 0; i < 8; ++i) { bestd[i] = 3.0e38f; bestj[i] = 0; }
  float Sreg[8];
#pragma unroll
  for (int rr = 0; rr < 8; ++rr) Sreg[rr] = S[nb + tr * 8 + rr];
  float4 pf[4];
#pragma unroll
  for (int q = 0; q < 4; ++q) {
    int cid = q * 256 + t;
    pf[q] = *(const float4*)(emb + (size_t)(cid >> 2) * DIM + (cid & 3) * 4);
  }
  for (int jt = 0; jt < KEMB / JT; ++jt) {
    float acc[8][8];
#pragma unroll
    for (int rr = 0; rr < 8; ++rr)
#pragma unroll
      for (int c = 0; c < 8; ++c) acc[rr][c] = 0.0f;
    for (int kc = 0; kc < DIM / KC; ++kc) {
      __syncthreads();
#pragma unroll
      for (int q = 0; q < 4; ++q) {
        int cid = q * 256 + t;
        int j = cid >> 2, k4 = cid & 3;
        et[(k4 * 4 + 0) * JT + j] = pf[q].x;
        et[(k4 * 4 + 1) * JT + j] = pf[q].y;
        et[(k4 * 4 + 2) * JT + j] = pf[q].z;
        et[(k4 * 4 + 3) * JT + j] = pf[q].w;
      }
      int s = jt * (DIM / KC) + kc + 1;
      if (s < (KEMB / JT) * (DIM / KC)) {
        int njt = s >> 4, nkc = s & 15;
        const float* base = emb + (size_t)njt * JT * DIM + nkc * KC;
#pragma unroll
        for (int q = 0; q < 4; ++q) {
          int cid = q * 256 + t;
          pf[q] = *(const float4*)(base + (size_t)(cid >> 2) * DIM + (cid & 3) * 4);
        }
      }
      __syncthreads();
      const float* ztk = zt + (kc * KC) * RT;
#pragma unroll
      for (int kk = 0; kk < KC; ++kk) {
        float4 z0 = *(const float4*)(ztk + kk * RT + tr * 8);
        float4 z1 = *(const float4*)(ztk + kk * RT + tr * 8 + 4);
        float2 e0 = *(const float2*)(et + kk * JT + g * 2);
        float2 e1 = *(const float2*)(et + kk * JT + 64 + g * 2);
        float2 e2 = *(const float2*)(et + kk * JT + 128 + g * 2);
        float2 e3 = *(const float2*)(et + kk * JT + 192 + g * 2);
        float zr[8] = {z0.x, z0.y, z0.z, z0.w, z1.x, z1.y, z1.z, z1.w};
        float ev[8] = {e0.x, e0.y, e1.x, e1.y, e2.x, e2.y, e3.x, e3.y};
#pragma unroll
        for (int rr = 0; rr < 8; ++rr)
#pragma unroll
          for (int c = 0; c < 8; ++c)
            acc[rr][c] = fmaf(zr[rr], ev[c], acc[rr][c]);
      }
    }
    int jb = jt * JT;
    float Ereg[8];
#pragma unroll
    for (int c = 0; c < 8; ++c)
      Ereg[c] = E[jb + (c >> 1) * 64 + g * 2 + (c & 1)];
#pragma unroll
    for (int rr = 0; rr < 8; ++rr)
#pragma unroll
      for (int c = 0; c < 8; ++c) {
        float A = Sreg[rr] + Ereg[c];
        float d = fmaf(-2.0f, acc[rr][c], A);
        int j = jb + (c >> 1) * 64 + g * 2 + (c & 1);
        if (d < bestd[rr] || (d == bestd[rr] && j < bestj[rr])) {
          bestd[rr] = d; bestj[rr] = j;
        }
      }
  }
  __syncthreads();
  float* rd = et;
  int*   rj = (int*)(et + 2048);
#pragma unroll
  for (int rr = 0; rr < 8; ++rr) {
    rd[(tr * 8 + rr) * 32 + g] = bestd[rr];
    rj[(tr * 8 + rr) * 32 + g] = bestj[rr];
  }
  __syncthreads();
  if (t < RT) {
    float bd = rd[t * 32];
    int   bj = rj[t * 32];
    for (int c = 1; c < 32; ++c) {
      float d2 = rd[t * 32 + c];
      int   j2 = rj[t * 32 + c];
      if (d2 < bd || (d2 == bd && j2 < bj)) { bd = d2; bj = j2; }
    }
    idx_out[nb + t]  = bj;
    idxf_out[nb + t] = (float)bj;
  }
}

// ---------- epilogue: gather + STE output + loss partials ----------
__global__ __launch_bounds__(256) void epilogue_kernel(
    const float* __restrict__ z, const float* __restrict__ emb,
    const int* __restrict__ idx, float* __restrict__ out0,
    double* __restrict__ loss_sum) {
#pragma clang fp contract(off)
  __shared__ double wsum[4];
  double acc = 0.0;
#pragma unroll
  for (int it = 0; it < 4; ++it) {
    int u = (it * 2048 + blockIdx.x) * 256 + threadIdx.x;
    int gid = u * 4;
    int hw = gid & 1023;
    int d  = (gid >> 10) & 255;
    int b  = gid >> 18;
    int n  = b * 1024 + hw;
    float4 zp = *(const float4*)(z + gid);
    int4 iv = *(const int4*)(idx + n);
    float q0 = emb[(size_t)iv.x * DIM + d];
    float q1 = emb[(size_t)iv.y * DIM + d];
    float q2 = emb[(size_t)iv.z * DIM + d];
    float q3 = emb[(size_t)iv.w * DIM + d];
    float t0 = q0 - zp.x, t1 = q1 - zp.y, t2 = q2 - zp.z, t3 = q3 - zp.w;
    float4 o; o.x = zp.x + t0; o.y = zp.y + t1; o.z = zp.z + t2; o.w = zp.w + t3;
    *(float4*)(out0 + gid) = o;
    acc += (double)(t0 * t0);
    acc += (double)(t1 * t1);
    acc += (double)(t2 * t2);
    acc += (double)(t3 * t3);
  }
#pragma unroll
  for (int off = 32; off > 0; off >>= 1) acc += __shfl_down(acc, off, 64);
  int lane = threadIdx.x & 63, wv = threadIdx.x >> 6;
  if (lane == 0) wsum[wv] = acc;
  __syncthreads();
  if (threadIdx.x == 0) {
    double bsum = (wsum[0] + wsum[1]) + (wsum[2] + wsum[3]);
    atomicAdd(loss_sum, bsum);
  }
}

// ---------- finalize loss ----------
__global__ void finalize_loss(const double* __restrict__ loss_sum,
                              float* __restrict__ out_loss) {
  double m = loss_sum[0] / 8388608.0;
  float mf = (float)m;
  float bb = 10.0f * mf;
  out_loss[0] = mf + bb;
}

extern "C" void kernel_launch(void* const* d_in, const int* in_sizes, int n_in,
                              void* d_out, int out_size, void* d_ws, size_t ws_size,
                              hipStream_t stream) {
  const float* z   = (const float*)d_in[0];
  const float* emb = (const float*)d_in[1];
  float* out = (float*)d_out;
  char* ws = (char*)d_ws;
  int*    idx = (int*)ws;
  float*  S   = (float*)(ws + WS_S_OFF);
  float*  E   = (float*)(ws + WS_E_OFF);
  double* ls  = (double*)(ws + WS_LOSS_OFF);

  // zero loss_sum + cnt in one async memset
  hipMemsetAsync(ws + WS_LOSS_OFF, 0, WS_CAND_OFF - WS_LOSS_OFF, stream);

  norms_kernel<<<144, 256, 0, stream>>>(z, emb, S, E);

  if (ws_size >= (size_t)WS_NEEDED) {
    int*   cnt  = (int*)(ws + WS_CNT_OFF);
    int*   cand = (int*)(ws + WS_CAND_OFF);
    short* ebuf = (short*)(ws + WS_EBUF_OFF);
    pack_e_kernel<<<512, 256, 0, stream>>>(emb, ebuf);
    filter2_kernel<<<512, 256, 0, stream>>>(z, ebuf, E, cnt, cand);
    exact_cand_kernel<<<128, 256, 0, stream>>>(z, emb, S, E, cnt, cand, idx,
                                               out + 8388609);
  } else {
    dist_argmin_kernel<<<NROWS / RT, 256, 0, stream>>>(z, emb, S, E, idx,
                                                       out + 8388609);
  }

  epilogue_kernel<<<2048, 256, 0, stream>>>(z, emb, idx, out, ls);
  finalize_loss<<<1, 1, 0, stream>>>(ls, out + 8388608);
}